// Round 3
// baseline (89.268 us; speedup 1.0000x reference)
//
#include <hip/hip_runtime.h>
#include <math.h>

#define B 96
#define D 512
#define MARGIN_TRIPLE 0.2f
#define MARGIN_INTER  0.1f
// Harness contract: d_ws is re-poisoned to 0xAA bytes before EVERY launch
// (correctness call and each timed graph replay). So the completion counter
// deterministically starts at 0xAAAAAAAA — no init kernel needed.
#define WS_POISON 0xAAAAAAAAu

__device__ __forceinline__ float dot_fold(float4 a, float4 b) {
    // contributes b*(b-2a) summed over the 4 components:
    // d^2 = ||ei||^2 + sum_k b_k*(b_k - 2 a_k)
    float c;
    c  = b.x * (b.x - 2.f * a.x);
    c += b.y * (b.y - 2.f * a.y);
    c += b.z * (b.z - 2.f * a.z);
    c += b.w * (b.w - 2.f * a.w);
    return c;
}

__global__ __launch_bounds__(256)
void bhq_fused(const float* __restrict__ embs, const int* __restrict__ idty,
               float* __restrict__ wsD, float* __restrict__ wsHP,
               float* __restrict__ wsHN, int* __restrict__ wsP,
               int* __restrict__ wsN, int* __restrict__ wsHas,
               unsigned* __restrict__ wsCnt, float* __restrict__ out)
{
    __shared__ float ei[D];
    __shared__ float drow[B];
    __shared__ int   y[B];
    __shared__ float ssred[4];
    __shared__ int   lastflag;
    __shared__ float hpS[B], hnS[B];
    __shared__ int   pS[B], nS[B], hasS[B];
    __shared__ float wsum[4];

    const int i    = blockIdx.x;
    const int tid  = threadIdx.x;
    const int wave = tid >> 6;
    const int lane = tid & 63;

    // ---- stage row i into LDS (float4), fused ||e_i||^2 partial ----
    float ss = 0.f;
    if (tid < 128) {
        float4 v = ((const float4*)(embs + i * D))[tid];
        ((float4*)ei)[tid] = v;
        ss = v.x * v.x + v.y * v.y + v.z * v.z + v.w * v.w;
    }
#pragma unroll
    for (int off = 32; off > 0; off >>= 1) ss += __shfl_xor(ss, off, 64);
    if (lane == 0) ssred[wave] = ss;
    if (tid < B) y[tid] = idty[tid];
    __syncthreads();
    const float ssi = ssred[0] + ssred[1] + ssred[2] + ssred[3];

    // ---- distance row: d(i,j)^2 = ssi + sum b*(b-2a); single reduce per j ----
    const float4* ei4 = (const float4*)ei;
    const float4  a0 = ei4[lane];
    const float4  a1 = ei4[lane + 64];
#pragma unroll 4
    for (int t = 0; t < B / 4; ++t) {
        const int j = wave + 4 * t;
        const float4* ej4 = (const float4*)(embs + j * D);
        float4 b0 = ej4[lane];
        float4 b1 = ej4[lane + 64];
        float  c  = dot_fold(a0, b0) + dot_fold(a1, b1);
#pragma unroll
        for (int off = 32; off > 0; off >>= 1) c += __shfl_xor(c, off, 64);
        if (lane == 0) {
            float v = fmaxf(ssi + c, 0.f);
            drow[j] = (j == i || v == 0.f) ? 0.f : sqrtf(v);
        }
    }
    __syncthreads();

    // ---- wave 0: batch-hard mining (first-occurrence ties, matching jnp) ----
    if (wave == 0) {
        const int  yr   = y[i];
        const int  j0   = lane, j1 = lane + 64;
        const bool has1 = (lane < B - 64);
        const float d0 = drow[j0];
        const float d1 = has1 ? drow[j1] : 0.f;
        const int   y0 = y[j0];
        const int   y1 = has1 ? y[j1] : -1;

        float mx = fmaxf(d0, has1 ? d1 : -INFINITY);
#pragma unroll
        for (int off = 32; off > 0; off >>= 1) mx = fmaxf(mx, __shfl_xor(mx, off, 64));

        const bool pos0 = (j0 != i) && (y0 == yr);
        const bool pos1 = has1 && (j1 != i) && (y1 == yr);
        float a0v = pos0 ? d0 : 0.f;
        float a1v = has1 ? (pos1 ? d1 : 0.f) : -INFINITY;
        float bv; int bi;
        if (a1v > a0v) { bv = a1v; bi = j1; } else { bv = a0v; bi = j0; }
#pragma unroll
        for (int off = 32; off > 0; off >>= 1) {
            float ov = __shfl_xor(bv, off, 64);
            int   oi = __shfl_xor(bi, off, 64);
            if (ov > bv || (ov == bv && oi < bi)) { bv = ov; bi = oi; }
        }

        float n0 = d0 + ((y0 == yr) ? mx : 0.f);
        float n1 = has1 ? (d1 + ((y1 == yr) ? mx : 0.f)) : INFINITY;
        float cv; int ci;
        if (n1 < n0) { cv = n1; ci = j1; } else { cv = n0; ci = j0; }
#pragma unroll
        for (int off = 32; off > 0; off >>= 1) {
            float ov = __shfl_xor(cv, off, 64);
            int   oi = __shfl_xor(ci, off, 64);
            if (ov < cv || (ov == cv && oi < ci)) { cv = ov; ci = oi; }
        }

        unsigned long long bal = __ballot(pos0 || pos1);
        if (lane == 0) {
            wsHP[i]  = bv;
            wsHN[i]  = cv;
            wsP[i]   = bi;
            wsN[i]   = ci;
            wsHas[i] = (bal != 0ULL) ? 1 : 0;
        }
    }
    if (tid < B) wsD[i * B + tid] = drow[tid];

    // ---- last-block-done handoff (device-scope release/acquire) ----
    __syncthreads();          // all block writes issued
    __threadfence();          // cumulative device-scope release
    if (tid == 0) {
        unsigned old = atomicAdd(wsCnt, 1u);
        lastflag = (old == WS_POISON + (unsigned)(B - 1)) ? 1 : 0;
    }
    __syncthreads();
    if (!lastflag) return;    // block-uniform
    __threadfence();          // acquire: see all other blocks' ws writes

    // ---- final O(B^2) reduce (last block only) ----
    if (tid < B) {
        hpS[tid]  = wsHP[tid];
        hnS[tid]  = wsHN[tid];
        pS[tid]   = wsP[tid];
        nS[tid]   = wsN[tid];
        hasS[tid] = wsHas[tid];
    }
    __syncthreads();

    float acc = 0.f;
    if (tid < B) acc = fmaxf(hpS[tid] - hnS[tid] + MARGIN_TRIPLE, 0.f) * (1.f / B);

    float il = 0.f;
    for (int idx = tid; idx < B * B; idx += 256) {
        const int x = idx / B, l = idx - x * B;
        const int px = pS[x], nx = nS[x];
        const int yp = y[px], yn = y[nx], yl = y[l];
        // qmask collapsed: y_p!=y_n, y_l!=y_p, y_l!=y_n, class(p) has >=2 members
        if (yp != yn && hasS[px] && yl != yp && yl != yn) {
            il += fmaxf(hpS[px] - wsD[nx * B + l] + MARGIN_INTER, 0.f);
        }
    }
    acc += il * (1.f / (B * B));

#pragma unroll
    for (int off = 32; off > 0; off >>= 1) acc += __shfl_xor(acc, off, 64);
    if ((tid & 63) == 0) wsum[tid >> 6] = acc;
    __syncthreads();
    if (tid == 0) out[0] = wsum[0] + wsum[1] + wsum[2] + wsum[3];
}

extern "C" void kernel_launch(void* const* d_in, const int* in_sizes, int n_in,
                              void* d_out, int out_size, void* d_ws, size_t ws_size,
                              hipStream_t stream) {
    const float* embs = (const float*)d_in[0];
    const int*   idty = (const int*)d_in[1];
    float*       out  = (float*)d_out;

    float*    wsD   = (float*)d_ws;      // B*B floats
    float*    wsHP  = wsD + B * B;
    float*    wsHN  = wsHP + B;
    int*      wsP   = (int*)(wsHN + B);
    int*      wsN   = wsP + B;
    int*      wsHas = wsN + B;
    unsigned* wsCnt = (unsigned*)(wsHas + B);

    bhq_fused<<<B, 256, 0, stream>>>(embs, idty, wsD, wsHP, wsHN, wsP, wsN,
                                     wsHas, wsCnt, out);
}

// Round 4
// 83.497 us; speedup vs baseline: 1.0691x; 1.0691x over previous
//
#include <hip/hip_runtime.h>
#include <math.h>

#define B 96
#define D 512
#define MARGIN_TRIPLE 0.2f
#define MARGIN_INTER  0.1f

__device__ __forceinline__ float dot_fold(float4 a, float4 b) {
    // contributes sum_k b_k*(b_k - 2 a_k):  d^2 = ||ei||^2 + sum b*(b-2a)
    float c;
    c  = b.x * (b.x - 2.f * a.x);
    c += b.y * (b.y - 2.f * a.y);
    c += b.z * (b.z - 2.f * a.z);
    c += b.w * (b.w - 2.f * a.w);
    return c;
}

// Kernel 1: one block per row i. float4 loads, folded norm+dot (one butterfly
// reduce per j), then wave-0 batch-hard mining with jnp first-occurrence ties.
// NOTE (R3 post-mortem): do NOT fuse the final reduce via last-block-done —
// 96 blocks' device-scope fence+atomic and cross-XCD reads cost ~5 µs vs ~1 µs
// for a second dispatch.
__global__ __launch_bounds__(256)
void bhq_rows(const float* __restrict__ embs, const int* __restrict__ idty,
              float* __restrict__ wsD, float* __restrict__ wsHP,
              float* __restrict__ wsHN, int* __restrict__ wsP,
              int* __restrict__ wsN, int* __restrict__ wsHas) {
    __shared__ float ei[D];
    __shared__ float drow[B];
    __shared__ int   y[B];
    __shared__ float ssred[4];

    const int i    = blockIdx.x;
    const int tid  = threadIdx.x;
    const int wave = tid >> 6;
    const int lane = tid & 63;

    // stage row i (float4), fused ||e_i||^2 partial
    float ss = 0.f;
    if (tid < 128) {
        float4 v = ((const float4*)(embs + i * D))[tid];
        ((float4*)ei)[tid] = v;
        ss = v.x * v.x + v.y * v.y + v.z * v.z + v.w * v.w;
    }
#pragma unroll
    for (int off = 32; off > 0; off >>= 1) ss += __shfl_xor(ss, off, 64);
    if (lane == 0) ssred[wave] = ss;
    if (tid < B) y[tid] = idty[tid];
    __syncthreads();
    const float ssi = ssred[0] + ssred[1] + ssred[2] + ssred[3];

    // distance row: one reduce per j
    const float4* ei4 = (const float4*)ei;
    const float4  a0 = ei4[lane];
    const float4  a1 = ei4[lane + 64];
#pragma unroll 4
    for (int t = 0; t < B / 4; ++t) {
        const int j = wave + 4 * t;
        const float4* ej4 = (const float4*)(embs + j * D);
        float4 b0 = ej4[lane];
        float4 b1 = ej4[lane + 64];
        float  c  = dot_fold(a0, b0) + dot_fold(a1, b1);
#pragma unroll
        for (int off = 32; off > 0; off >>= 1) c += __shfl_xor(c, off, 64);
        if (lane == 0) {
            float v = fmaxf(ssi + c, 0.f);
            drow[j] = (j == i || v == 0.f) ? 0.f : sqrtf(v);
        }
    }
    __syncthreads();

    // wave 0: batch-hard mining (first-occurrence ties, matching jnp)
    if (wave == 0) {
        const int  yr   = y[i];
        const int  j0   = lane, j1 = lane + 64;
        const bool has1 = (lane < B - 64);
        const float d0 = drow[j0];
        const float d1 = has1 ? drow[j1] : 0.f;
        const int   y0 = y[j0];
        const int   y1 = has1 ? y[j1] : -1;

        float mx = fmaxf(d0, has1 ? d1 : -INFINITY);
#pragma unroll
        for (int off = 32; off > 0; off >>= 1) mx = fmaxf(mx, __shfl_xor(mx, off, 64));

        const bool pos0 = (j0 != i) && (y0 == yr);
        const bool pos1 = has1 && (j1 != i) && (y1 == yr);
        float a0v = pos0 ? d0 : 0.f;
        float a1v = has1 ? (pos1 ? d1 : 0.f) : -INFINITY;
        float bv; int bi;
        if (a1v > a0v) { bv = a1v; bi = j1; } else { bv = a0v; bi = j0; }
#pragma unroll
        for (int off = 32; off > 0; off >>= 1) {
            float ov = __shfl_xor(bv, off, 64);
            int   oi = __shfl_xor(bi, off, 64);
            if (ov > bv || (ov == bv && oi < bi)) { bv = ov; bi = oi; }
        }

        float n0 = d0 + ((y0 == yr) ? mx : 0.f);
        float n1 = has1 ? (d1 + ((y1 == yr) ? mx : 0.f)) : INFINITY;
        float cv; int ci;
        if (n1 < n0) { cv = n1; ci = j1; } else { cv = n0; ci = j0; }
#pragma unroll
        for (int off = 32; off > 0; off >>= 1) {
            float ov = __shfl_xor(cv, off, 64);
            int   oi = __shfl_xor(ci, off, 64);
            if (ov < cv || (ov == cv && oi < ci)) { cv = ov; ci = oi; }
        }

        unsigned long long bal = __ballot(pos0 || pos1);
        if (lane == 0) {
            wsHP[i]  = bv;
            wsHN[i]  = cv;
            wsP[i]   = bi;
            wsN[i]   = ci;
            wsHas[i] = (bal != 0ULL) ? 1 : 0;
        }
    }
    if (tid < B) wsD[i * B + tid] = drow[tid];
}

// Kernel 2: tiny O(B^2) final reduce (collapsed quadruplet term + triplet mean)
__global__ __launch_bounds__(256)
void bhq_final(const float* __restrict__ wsD, const float* __restrict__ wsHP,
               const float* __restrict__ wsHN, const int* __restrict__ wsP,
               const int* __restrict__ wsN, const int* __restrict__ wsHas,
               const int* __restrict__ idty, float* __restrict__ out) {
    __shared__ float hp[B], hn[B];
    __shared__ int   p[B], n[B], has[B], y[B];
    __shared__ float wsum[4];
    const int tid = threadIdx.x;
    if (tid < B) {
        hp[tid]  = wsHP[tid];
        hn[tid]  = wsHN[tid];
        p[tid]   = wsP[tid];
        n[tid]   = wsN[tid];
        has[tid] = wsHas[tid];
        y[tid]   = idty[tid];
    }
    __syncthreads();

    float acc = 0.f;
    if (tid < B) acc = fmaxf(hp[tid] - hn[tid] + MARGIN_TRIPLE, 0.f) * (1.f / B);

    float il = 0.f;
    for (int idx = tid; idx < B * B; idx += 256) {
        const int x = idx / B, l = idx - x * B;
        const int px = p[x], nx = n[x];
        const int yp = y[px], yn = y[nx], yl = y[l];
        // qmask collapsed: y_p!=y_n, y_l!=y_p, y_l!=y_n, class(p) has >=2 members
        if (yp != yn && has[px] && yl != yp && yl != yn) {
            il += fmaxf(hp[px] - wsD[nx * B + l] + MARGIN_INTER, 0.f);
        }
    }
    acc += il * (1.f / (B * B));

#pragma unroll
    for (int off = 32; off > 0; off >>= 1) acc += __shfl_xor(acc, off, 64);
    if ((tid & 63) == 0) wsum[tid >> 6] = acc;
    __syncthreads();
    if (tid == 0) out[0] = wsum[0] + wsum[1] + wsum[2] + wsum[3];
}

extern "C" void kernel_launch(void* const* d_in, const int* in_sizes, int n_in,
                              void* d_out, int out_size, void* d_ws, size_t ws_size,
                              hipStream_t stream) {
    const float* embs = (const float*)d_in[0];
    const int*   idty = (const int*)d_in[1];
    float*       out  = (float*)d_out;

    float* wsD   = (float*)d_ws;        // B*B floats
    float* wsHP  = wsD + B * B;
    float* wsHN  = wsHP + B;
    int*   wsP   = (int*)(wsHN + B);
    int*   wsN   = wsP + B;
    int*   wsHas = wsN + B;

    bhq_rows<<<B, 256, 0, stream>>>(embs, idty, wsD, wsHP, wsHN, wsP, wsN, wsHas);
    bhq_final<<<1, 256, 0, stream>>>(wsD, wsHP, wsHN, wsP, wsN, wsHas, idty, out);
}